// Round 1
// baseline (1059.820 us; speedup 1.0000x reference)
//
#include <hip/hip_runtime.h>

#define ROI 268
#define NG 512
#define NNODES (NG * ROI)   // 137216
#define CH 32
#define SLOPE 0.33f
#define BN_EPS 1e-5f
#define LS 33               // padded LDS row stride for 268x32 tiles

__device__ __forceinline__ float leakyf(float v) {
    return v > 0.f ? v : SLOPE * v;
}

// ---------------------------------------------------------------------------
// K1: y0[N,32] = x[N,268] @ W1_0[268,32]   (fp32 vector GEMM)
// block: 256 threads -> 256 rows x 32 cols; thread tile 4 rows x 8 cols
// ---------------------------------------------------------------------------
__global__ __launch_bounds__(256, 2) void k_gemm1(
    const float* __restrict__ x, const float* __restrict__ W1,
    float* __restrict__ y0) {
    __shared__ float sW[ROI * CH];   // 8576 floats
    __shared__ float sA[32 * 260];   // k-major A tile, row-dim stride 260

    const int tid = threadIdx.x;
    const size_t rowbase = (size_t)blockIdx.x * 256;

    for (int i = tid; i < (ROI * CH) / 4; i += 256)
        ((float4*)sW)[i] = ((const float4*)W1)[i];

    float acc[4][8];
#pragma unroll
    for (int r = 0; r < 4; r++)
#pragma unroll
        for (int c = 0; c < 8; c++) acc[r][c] = 0.f;

    const int rg = tid >> 2;   // 0..63
    const int cg = tid & 3;    // 0..3

    int k0 = 0;
    for (int chunk = 0; chunk < 9; ++chunk) {
        const int ksize = (chunk < 8) ? 32 : 12;   // 268 = 8*32 + 12
        __syncthreads();
        const int nf4 = (ksize >> 2) << 8;
        for (int f = tid; f < nf4; f += 256) {
            int row, kk;
            if (ksize == 32) { row = f >> 3; kk = (f & 7) << 2; }
            else             { row = f & 255; kk = (f >> 8) << 2; }
            float4 v = *(const float4*)&x[(rowbase + row) * ROI + k0 + kk];
            sA[(kk + 0) * 260 + row] = v.x;
            sA[(kk + 1) * 260 + row] = v.y;
            sA[(kk + 2) * 260 + row] = v.z;
            sA[(kk + 3) * 260 + row] = v.w;
        }
        __syncthreads();
#pragma unroll 4
        for (int kk = 0; kk < ksize; ++kk) {
            float4 a4 = *(float4*)&sA[kk * 260 + rg * 4];
            const float* wr = &sW[(k0 + kk) * CH + cg * 8];
            float4 w0 = *(const float4*)wr;
            float4 w1 = *(const float4*)(wr + 4);
            float av[4] = {a4.x, a4.y, a4.z, a4.w};
            float wv[8] = {w0.x, w0.y, w0.z, w0.w, w1.x, w1.y, w1.z, w1.w};
#pragma unroll
            for (int r = 0; r < 4; r++)
#pragma unroll
                for (int c = 0; c < 8; c++) acc[r][c] += av[r] * wv[c];
        }
        k0 += ksize;
    }

#pragma unroll
    for (int r = 0; r < 4; r++) {
        size_t row = rowbase + rg * 4 + r;
        float4 o0 = make_float4(acc[r][0], acc[r][1], acc[r][2], acc[r][3]);
        float4 o1 = make_float4(acc[r][4], acc[r][5], acc[r][6], acc[r][7]);
        *(float4*)&y0[row * CH + cg * 8] = o0;
        *(float4*)&y0[row * CH + cg * 8 + 4] = o1;
    }
}

// ---------------------------------------------------------------------------
// K2: bucket edges by graph
// ---------------------------------------------------------------------------
__global__ void k_hist(const int* __restrict__ dst, int E, int* __restrict__ cnt) {
    __shared__ int h[NG];
    for (int i = threadIdx.x; i < NG; i += blockDim.x) h[i] = 0;
    __syncthreads();
    int stride = gridDim.x * blockDim.x;
    for (int i = blockIdx.x * blockDim.x + threadIdx.x; i < E; i += stride)
        atomicAdd(&h[dst[i] / ROI], 1);
    __syncthreads();
    for (int i = threadIdx.x; i < NG; i += blockDim.x)
        if (h[i]) atomicAdd(&cnt[i], h[i]);
}

__global__ void k_scan(const int* __restrict__ cnt, int* __restrict__ off,
                       int* __restrict__ cur) {
    __shared__ int s[NG];
    int t = threadIdx.x;   // 512 threads
    int myc = cnt[t];
    s[t] = myc;
    __syncthreads();
    for (int d = 1; d < NG; d <<= 1) {
        int v = (t >= d) ? s[t - d] : 0;
        __syncthreads();
        s[t] += v;
        __syncthreads();
    }
    int inc = s[t];
    int exc = inc - myc;
    off[t] = exc;
    cur[t] = exc;
    if (t == NG - 1) off[NG] = inc;
}

__global__ void k_scatter(const int* __restrict__ src, const int* __restrict__ dst,
                          int E, int* __restrict__ cur, int* __restrict__ packed) {
    int stride = gridDim.x * blockDim.x;
    for (int i = blockIdx.x * blockDim.x + threadIdx.x; i < E; i += stride) {
        int d = dst[i];
        int g = d / ROI;
        int s_ = src[i];
        int pos = atomicAdd(&cur[g], 1);
        packed[pos] = (s_ - g * ROI) | ((d - g * ROI) << 9);
    }
}

// ---------------------------------------------------------------------------
// K3 helpers
// ---------------------------------------------------------------------------
__device__ __forceinline__ void edge_agg(const float* __restrict__ yb,
                                         float* __restrict__ ab,
                                         const int* __restrict__ ep, int nE,
                                         int tid) {
    const int ch = tid & 31;
    const int e0 = tid >> 5;   // 0..7
    int i = e0;
    for (; i + 24 < nE; i += 32) {
        int p0 = ep[i], p1 = ep[i + 8], p2 = ep[i + 16], p3 = ep[i + 24];
        atomicAdd(&ab[((p0 >> 9) & 511) * LS + ch], yb[(p0 & 511) * LS + ch]);
        atomicAdd(&ab[((p1 >> 9) & 511) * LS + ch], yb[(p1 & 511) * LS + ch]);
        atomicAdd(&ab[((p2 >> 9) & 511) * LS + ch], yb[(p2 & 511) * LS + ch]);
        atomicAdd(&ab[((p3 >> 9) & 511) * LS + ch], yb[(p3 & 511) * LS + ch]);
    }
    for (; i < nE; i += 8) {
        int p = ep[i];
        atomicAdd(&ab[((p >> 9) & 511) * LS + ch], yb[(p & 511) * LS + ch]);
    }
}

// out[268,32] = (AFFINE ? leaky(bn(in @ w + bias)) : in @ w); LDS->LDS, stride LS
template <bool AFFINE>
__device__ __forceinline__ void gemm_stage(const float* __restrict__ in,
                                           float* __restrict__ out,
                                           const float* __restrict__ w,
                                           const float* __restrict__ bias,
                                           const float* __restrict__ sc,
                                           const float* __restrict__ sh, int tid) {
    for (int unit = tid; unit < ROI; unit += 256) {   // 134 rgs x 2 cgs
        const int rg = unit >> 1;
        const int cg = unit & 1;
        const int r0 = rg << 1;
        float acc0[16], acc1[16];
#pragma unroll
        for (int c = 0; c < 16; c++) {
            float b = AFFINE ? bias[cg * 16 + c] : 0.f;
            acc0[c] = b;
            acc1[c] = b;
        }
        const float* in0 = &in[r0 * LS];
        const float* in1 = in0 + LS;
#pragma unroll 8
        for (int k = 0; k < CH; k++) {
            float a0 = in0[k], a1 = in1[k];
            const float* wr = &w[k * CH + cg * 16];
            float4 w0 = *(const float4*)wr;
            float4 w1 = *(const float4*)(wr + 4);
            float4 w2 = *(const float4*)(wr + 8);
            float4 w3 = *(const float4*)(wr + 12);
            float wv[16] = {w0.x, w0.y, w0.z, w0.w, w1.x, w1.y, w1.z, w1.w,
                            w2.x, w2.y, w2.z, w2.w, w3.x, w3.y, w3.z, w3.w};
#pragma unroll
            for (int c = 0; c < 16; c++) {
                acc0[c] += a0 * wv[c];
                acc1[c] += a1 * wv[c];
            }
        }
        float* o0 = &out[r0 * LS + cg * 16];
        float* o1 = o0 + LS;
#pragma unroll
        for (int c = 0; c < 16; c++) {
            float h0v = acc0[c], h1v = acc1[c];
            if (AFFINE) {
                float s = sc[cg * 16 + c], t2 = sh[cg * 16 + c];
                h0v = leakyf(h0v * s + t2);
                h1v = leakyf(h1v * s + t2);
            }
            o0[c] = h0v;
            o1[c] = h1v;
        }
    }
}

__device__ __forceinline__ void pool_partial(const float* __restrict__ hb,
                                             float* __restrict__ psum,
                                             float* __restrict__ pmax, int tid) {
    const int ch = tid & 31;
    const int chunk = tid >> 5;
    float s = 0.f, m = -1e30f;
    for (int r = chunk; r < ROI; r += 8) {
        float v = hb[r * LS + ch];
        s += v;
        m = fmaxf(m, v);
    }
    psum[chunk * CH + ch] = s;
    pmax[chunk * CH + ch] = m;
}

__device__ __forceinline__ void pool_final(const float* __restrict__ psum,
                                           const float* __restrict__ pmax,
                                           float* __restrict__ zg, int tid) {
    if (tid < CH) {
        float s = psum[tid], m = pmax[tid];
#pragma unroll
        for (int j = 1; j < 8; j++) {
            s += psum[j * CH + tid];
            m = fmaxf(m, pmax[j * CH + tid]);
        }
        zg[tid] = m;                     // max first (ref: concat([mx, mn]))
        zg[CH + tid] = s / (float)ROI;   // mean
    }
}

// ---------------------------------------------------------------------------
// K3: fused both GIN layers + both poolings. One block per graph.
// ---------------------------------------------------------------------------
__global__ __launch_bounds__(256, 2) void k_gin(
    const float* __restrict__ y0, const int* __restrict__ packed,
    const int* __restrict__ off, const float* __restrict__ eps0p,
    const float* __restrict__ b1_0, const float* __restrict__ W2_0,
    const float* __restrict__ b2_0, const float* __restrict__ bn0_g,
    const float* __restrict__ bn0_b, const float* __restrict__ bn0_m,
    const float* __restrict__ bn0_v, const float* __restrict__ eps1p,
    const float* __restrict__ W1_1, const float* __restrict__ b1_1,
    const float* __restrict__ W2_1, const float* __restrict__ b2_1,
    const float* __restrict__ bn1_g, const float* __restrict__ bn1_b,
    const float* __restrict__ bn1_m, const float* __restrict__ bn1_v,
    float* __restrict__ z) {
    __shared__ float bufA[ROI * LS];   // 8844 floats
    __shared__ float bufB[ROI * LS];
    __shared__ float w[CH * CH];
    __shared__ float prm[8 * CH];      // b1_0,b2_0,sc0,sh0,b1_1,b2_1,sc1,sh1
    __shared__ float psum[8 * CH], pmax[8 * CH];
    __shared__ float epss[2];

    const int tid = threadIdx.x;
    const int g = blockIdx.x;

    if (tid < CH) {
        prm[0 * CH + tid] = b1_0[tid];
        prm[1 * CH + tid] = b2_0[tid];
        float s0 = bn0_g[tid] * rsqrtf(bn0_v[tid] + BN_EPS);
        prm[2 * CH + tid] = s0;
        prm[3 * CH + tid] = bn0_b[tid] - bn0_m[tid] * s0;
        prm[4 * CH + tid] = b1_1[tid];
        prm[5 * CH + tid] = b2_1[tid];
        float s1 = bn1_g[tid] * rsqrtf(bn1_v[tid] + BN_EPS);
        prm[6 * CH + tid] = s1;
        prm[7 * CH + tid] = bn1_b[tid] - bn1_m[tid] * s1;
    }
    if (tid == 0) {
        epss[0] = 1.0f + *eps0p;
        epss[1] = 1.0f + *eps1p;
    }
    // stage 0: y -> bufA (padded), zero bufB, w <- W2_0
    const float* yg = y0 + (size_t)g * ROI * CH;
    for (int f = tid; f < (ROI * CH) / 4; f += 256) {
        float4 v = ((const float4*)yg)[f];
        int row = f >> 3, kk = (f & 7) << 2;
        float* p = &bufA[row * LS + kk];
        p[0] = v.x; p[1] = v.y; p[2] = v.z; p[3] = v.w;
    }
    for (int i = tid; i < ROI * LS; i += 256) bufB[i] = 0.f;
    for (int i = tid; i < (CH * CH) / 4; i += 256)
        ((float4*)w)[i] = ((const float4*)W2_0)[i];
    __syncthreads();

    const int base = off[g];
    const int nE = off[g + 1] - base;

    // layer 0 aggregation: bufB = segment_sum(y)
    edge_agg(bufA, bufB, packed + base, nE, tid);
    __syncthreads();

    // A0 = leaky((1+eps0)*y + agg + b1_0), in place in bufA
    {
        float e0 = epss[0];
        for (int i = tid; i < ROI * CH; i += 256) {
            int row = i >> 5, c = i & 31;
            float v = e0 * bufA[row * LS + c] + bufB[row * LS + c] + prm[0 * CH + c];
            bufA[row * LS + c] = leakyf(v);
        }
    }
    __syncthreads();

    // h0 = leaky(bn(A0 @ W2_0 + b2_0)) -> bufB
    gemm_stage<true>(bufA, bufB, w, &prm[1 * CH], &prm[2 * CH], &prm[3 * CH], tid);
    __syncthreads();

    // pool0 partials + load w <- W1_1
    pool_partial(bufB, psum, pmax, tid);
    for (int i = tid; i < (CH * CH) / 4; i += 256)
        ((float4*)w)[i] = ((const float4*)W1_1)[i];
    __syncthreads();

    pool_final(psum, pmax, z + (size_t)g * 128, tid);

    // y1 = h0 @ W1_1 -> bufA
    gemm_stage<false>(bufB, bufA, w, nullptr, nullptr, nullptr, tid);
    __syncthreads();

    for (int i = tid; i < ROI * LS; i += 256) bufB[i] = 0.f;
    __syncthreads();

    // layer 1 aggregation
    edge_agg(bufA, bufB, packed + base, nE, tid);
    __syncthreads();

    // A1 = leaky((1+eps1)*y1 + agg1 + b1_1) in place; load w <- W2_1
    {
        float e1 = epss[1];
        for (int i = tid; i < ROI * CH; i += 256) {
            int row = i >> 5, c = i & 31;
            float v = e1 * bufA[row * LS + c] + bufB[row * LS + c] + prm[4 * CH + c];
            bufA[row * LS + c] = leakyf(v);
        }
    }
    for (int i = tid; i < (CH * CH) / 4; i += 256)
        ((float4*)w)[i] = ((const float4*)W2_1)[i];
    __syncthreads();

    // h1 = leaky(bn(A1 @ W2_1 + b2_1)) -> bufB
    gemm_stage<true>(bufA, bufB, w, &prm[5 * CH], &prm[6 * CH], &prm[7 * CH], tid);
    __syncthreads();

    pool_partial(bufB, psum, pmax, tid);
    __syncthreads();
    pool_final(psum, pmax, z + (size_t)g * 128 + 64, tid);
}

// ---------------------------------------------------------------------------
// K4: head MLP  z[512,128] -> 256 -> 128 -> 1
// ---------------------------------------------------------------------------
__global__ __launch_bounds__(256) void k_head(
    const float* __restrict__ z, const float* __restrict__ W1,
    const float* __restrict__ b1, const float* __restrict__ g1,
    const float* __restrict__ be1, const float* __restrict__ m1,
    const float* __restrict__ v1, const float* __restrict__ W2,
    const float* __restrict__ b2, const float* __restrict__ g2,
    const float* __restrict__ be2, const float* __restrict__ m2,
    const float* __restrict__ v2, const float* __restrict__ W3,
    const float* __restrict__ b3, float* __restrict__ out) {
    __shared__ float zr[128], z1[256], z2[128];
    const int t = threadIdx.x;
    const int g = blockIdx.x;

    if (t < 32) ((float4*)zr)[t] = ((const float4*)(z + (size_t)g * 128))[t];
    __syncthreads();
    {
        float acc = b1[t];
#pragma unroll 8
        for (int k = 0; k < 128; k++) acc += zr[k] * W1[k * 256 + t];
        float s = g1[t] * rsqrtf(v1[t] + BN_EPS);
        acc = (acc - m1[t]) * s + be1[t];
        z1[t] = leakyf(acc);
    }
    __syncthreads();
    if (t < 128) {
        float acc = b2[t];
#pragma unroll 8
        for (int k = 0; k < 256; k++) acc += z1[k] * W2[k * 128 + t];
        float s = g2[t] * rsqrtf(v2[t] + BN_EPS);
        acc = (acc - m2[t]) * s + be2[t];
        z2[t] = leakyf(acc);
    }
    __syncthreads();
    if (t < 64) {
        float v = z2[t] * W3[t] + z2[t + 64] * W3[t + 64];
        for (int offd = 32; offd; offd >>= 1) v += __shfl_down(v, offd);
        if (t == 0) out[g] = v + b3[0];
    }
}

// ---------------------------------------------------------------------------
extern "C" void kernel_launch(void* const* d_in, const int* in_sizes, int n_in,
                              void* d_out, int out_size, void* d_ws, size_t ws_size,
                              hipStream_t stream) {
    const float* x      = (const float*)d_in[0];
    const int* eidx     = (const int*)d_in[1];
    const float* eps0   = (const float*)d_in[3];
    const float* W1_0   = (const float*)d_in[4];
    const float* b1_0   = (const float*)d_in[5];
    const float* W2_0   = (const float*)d_in[6];
    const float* b2_0   = (const float*)d_in[7];
    const float* bn0_g  = (const float*)d_in[8];
    const float* bn0_b  = (const float*)d_in[9];
    const float* bn0_m  = (const float*)d_in[10];
    const float* bn0_v  = (const float*)d_in[11];
    const float* eps1   = (const float*)d_in[12];
    const float* W1_1   = (const float*)d_in[13];
    const float* b1_1   = (const float*)d_in[14];
    const float* W2_1   = (const float*)d_in[15];
    const float* b2_1   = (const float*)d_in[16];
    const float* bn1_g  = (const float*)d_in[17];
    const float* bn1_b  = (const float*)d_in[18];
    const float* bn1_m  = (const float*)d_in[19];
    const float* bn1_v  = (const float*)d_in[20];
    const float* lin1_W = (const float*)d_in[21];
    const float* lin1_b = (const float*)d_in[22];
    const float* hbn1_g = (const float*)d_in[23];
    const float* hbn1_b = (const float*)d_in[24];
    const float* hbn1_m = (const float*)d_in[25];
    const float* hbn1_v = (const float*)d_in[26];
    const float* lin2_W = (const float*)d_in[27];
    const float* lin2_b = (const float*)d_in[28];
    const float* hbn2_g = (const float*)d_in[29];
    const float* hbn2_b = (const float*)d_in[30];
    const float* hbn2_m = (const float*)d_in[31];
    const float* hbn2_v = (const float*)d_in[32];
    const float* lin3_W = (const float*)d_in[33];
    const float* lin3_b = (const float*)d_in[34];

    const int E = in_sizes[1] / 2;
    const int* src = eidx;
    const int* dst = eidx + E;

    char* ws = (char*)d_ws;
    const size_t Y0_OFF  = 0;
    const size_t Z_OFF   = (size_t)NNODES * CH * 4;        // 17,563,648
    const size_t CNT_OFF = Z_OFF + (size_t)NG * 128 * 4;   // +262,144
    const size_t CUR_OFF = CNT_OFF + 2048;
    const size_t OFF_OFF = CUR_OFF + 2048;
    const size_t PKD_OFF = OFF_OFF + 2304;

    float* y0    = (float*)(ws + Y0_OFF);
    float* z     = (float*)(ws + Z_OFF);
    int* cnt     = (int*)(ws + CNT_OFF);
    int* cur     = (int*)(ws + CUR_OFF);
    int* off     = (int*)(ws + OFF_OFF);
    int* packed  = (int*)(ws + PKD_OFF);

    k_gemm1<<<NNODES / 256, 256, 0, stream>>>(x, W1_0, y0);

    hipMemsetAsync(cnt, 0, NG * sizeof(int), stream);
    k_hist<<<256, 256, 0, stream>>>(dst, E, cnt);
    k_scan<<<1, NG, 0, stream>>>(cnt, off, cur);
    k_scatter<<<512, 256, 0, stream>>>(src, dst, E, cur, packed);

    k_gin<<<NG, 256, 0, stream>>>(y0, packed, off, eps0, b1_0, W2_0, b2_0,
                                  bn0_g, bn0_b, bn0_m, bn0_v, eps1, W1_1, b1_1,
                                  W2_1, b2_1, bn1_g, bn1_b, bn1_m, bn1_v, z);

    k_head<<<NG, 256, 0, stream>>>(z, lin1_W, lin1_b, hbn1_g, hbn1_b, hbn1_m,
                                   hbn1_v, lin2_W, lin2_b, hbn2_g, hbn2_b,
                                   hbn2_m, hbn2_v, lin3_W, lin3_b,
                                   (float*)d_out);
}